// Round 2
// baseline (5275.771 us; speedup 1.0000x reference)
//
#include <hip/hip_runtime.h>
#include <hip/hip_fp16.h>

#define TT 512
#define BB 2048
#define HH 256
#define KCH 64

__device__ __forceinline__ float sigf(float z) { return 1.0f / (1.0f + __expf(-z)); }
// order-preserving float<->uint for atomic min/max
__device__ __forceinline__ unsigned f2o(float f) {
    unsigned u = __float_as_uint(f);
    return (u & 0x80000000u) ? ~u : (u | 0x80000000u);
}
__device__ __forceinline__ float o2f(unsigned o) {
    unsigned u = (o & 0x80000000u) ? (o & 0x7fffffffu) : ~o;
    return __uint_as_float(u);
}

// K0: per-t column min/max of X -> analytic min/max of out1_pre; init atomics + state.
__global__ __launch_bounds__(256) void k0_stats(const float* __restrict__ X,
                                                const float* __restrict__ W1,
                                                const float* __restrict__ b1,
                                                float* __restrict__ mn1f, float* __restrict__ s1f,
                                                unsigned* __restrict__ uo,
                                                float2* __restrict__ statep) {
    int t = blockIdx.x, tid = threadIdx.x;
    // zero the scan state (ws is poisoned once, never re-poisoned between replays)
    statep[blockIdx.x * 256 + tid] = make_float2(0.f, 0.f);
    __shared__ float rmn[256], rmx[256];
    float mn = 3.4e38f, mx = -3.4e38f;
    for (int b = tid; b < BB; b += 256) {
        float v = X[(size_t)b * TT + t];
        mn = fminf(mn, v); mx = fmaxf(mx, v);
    }
    rmn[tid] = mn; rmx[tid] = mx; __syncthreads();
    for (int s = 128; s > 0; s >>= 1) {
        if (tid < s) { rmn[tid] = fminf(rmn[tid], rmn[tid + s]); rmx[tid] = fmaxf(rmx[tid], rmx[tid + s]); }
        __syncthreads();
    }
    float xmn = rmn[0], xmx = rmx[0];
    __syncthreads();
    float w = W1[tid], bb = b1[tid];
    float v0 = w * xmn + bb, v1 = w * xmx + bb;
    rmn[tid] = fminf(v0, v1); rmx[tid] = fmaxf(v0, v1); __syncthreads();
    for (int s = 128; s > 0; s >>= 1) {
        if (tid < s) { rmn[tid] = fminf(rmn[tid], rmn[tid + s]); rmx[tid] = fmaxf(rmx[tid], rmx[tid + s]); }
        __syncthreads();
    }
    if (tid == 0) {
        float m0 = rmn[0], m1 = rmx[0];
        mn1f[t] = m0; s1f[t] = 20.0f / (m1 - m0);
        uo[t] = 0xFFFFFFFFu; uo[512 + t] = 0u;          // out2_pre min/max
        uo[1024 + t] = 0xFFFFFFFFu; uo[1536 + t] = 0u;  // jpre
        uo[2048 + t] = 0xFFFFFFFFu; uo[2560 + t] = 0u;  // kpre
    }
}

// K1: out2_pre[tl,b,:] = W2 @ out1[t,b,:] + b2, out1 generated on the fly. fp32 out.
__global__ __launch_bounds__(256) void k1_gemm(const float* __restrict__ X,
                                               const float* __restrict__ W1,
                                               const float* __restrict__ b1,
                                               const float* __restrict__ W2,
                                               const float* __restrict__ b2,
                                               const float* __restrict__ mn1f,
                                               const float* __restrict__ s1f,
                                               float* __restrict__ buf,
                                               unsigned* __restrict__ uo,
                                               int tbase) {
    int tl = blockIdx.z;
    int t = tbase + tl;
    int bBase = blockIdx.x * 64;
    int cBase = blockIdx.y * 64;
    int tid = threadIdx.x;
    __shared__ __align__(16) float a_lds[KCH][68];
    __shared__ __align__(16) float w_lds[KCH][68];
    __shared__ float x_s[64];
    if (tid < 64) x_s[tid] = X[(size_t)(bBase + tid) * TT + t];
    float mn1 = mn1f[t], s1 = s1f[t];
    float acc[4][4];
#pragma unroll
    for (int r = 0; r < 4; ++r)
#pragma unroll
        for (int c = 0; c < 4; ++c) acc[r][c] = 0.f;
    int tx = tid & 15, ty = tid >> 4;
    for (int k0 = 0; k0 < HH; k0 += KCH) {
        __syncthreads();  // covers x_s on first iter, LDS reuse later
#pragma unroll
        for (int i = 0; i < 16; ++i) {  // stage out1 tile, k-major [ki][r]
            int idx = i * 256 + tid;
            int ki = idx >> 6, r = idx & 63;
            int k = k0 + ki;
            float v = x_s[r] * W1[k] + b1[k];
            a_lds[ki][r] = sigf((v - mn1) * s1);
        }
#pragma unroll
        for (int i = 0; i < 16; ++i) {  // stage W2 tile, k-major [ki][c]
            int idx = i * 256 + tid;
            int ki = idx & 63, c = idx >> 6;
            w_lds[ki][c] = W2[(size_t)(cBase + c) * HH + k0 + ki];
        }
        __syncthreads();
#pragma unroll
        for (int ki = 0; ki < KCH; ++ki) {
            float4 av = *(const float4*)&a_lds[ki][ty * 4];
            float4 wv = *(const float4*)&w_lds[ki][tx * 4];
            float aa[4] = {av.x, av.y, av.z, av.w};
            float ww[4] = {wv.x, wv.y, wv.z, wv.w};
#pragma unroll
            for (int r = 0; r < 4; ++r)
#pragma unroll
                for (int c = 0; c < 4; ++c) acc[r][c] = __fmaf_rn(aa[r], ww[c], acc[r][c]);
        }
    }
    int col0 = cBase + tx * 4;
    float bb0 = b2[col0], bb1 = b2[col0 + 1], bb2v = b2[col0 + 2], bb3 = b2[col0 + 3];
    float lmn = 3.4e38f, lmx = -3.4e38f;
#pragma unroll
    for (int r = 0; r < 4; ++r) {
        int row = bBase + ty * 4 + r;
        float v0 = acc[r][0] + bb0, v1 = acc[r][1] + bb1, v2 = acc[r][2] + bb2v, v3 = acc[r][3] + bb3;
        lmn = fminf(lmn, fminf(fminf(v0, v1), fminf(v2, v3)));
        lmx = fmaxf(lmx, fmaxf(fmaxf(v0, v1), fmaxf(v2, v3)));
        float4 st = make_float4(v0, v1, v2, v3);
        *(float4*)&buf[((size_t)tl * BB + row) * HH + col0] = st;
    }
    __syncthreads();
    float* red = &a_lds[0][0];
    float* red2 = &w_lds[0][0];
    red[tid] = lmn; red2[tid] = lmx; __syncthreads();
    for (int s = 128; s > 0; s >>= 1) {
        if (tid < s) { red[tid] = fminf(red[tid], red[tid + s]); red2[tid] = fmaxf(red2[tid], red2[tid + s]); }
        __syncthreads();
    }
    if (tid == 0) {
        atomicMin(&uo[t], f2o(red[0]));
        atomicMax(&uo[512 + t], f2o(red2[0]));
    }
}

__global__ void k1b(const unsigned* __restrict__ uo, float* __restrict__ mn2f,
                    float* __restrict__ s2f, int tbase) {
    int t = tbase + threadIdx.x;
    float mn = o2f(uo[t]), mx = o2f(uo[512 + t]);
    mn2f[t] = mn; s2f[t] = 20.0f / (mx - mn);
}

// K2: in-place out2_pre -> jpre/kpre (post-sigmoid * j_w/k_w), per-t min/max atomics. fp32.
__global__ __launch_bounds__(256) void k2_jk(float* __restrict__ buf,
                                             const float* __restrict__ mn2f,
                                             const float* __restrict__ s2f,
                                             const float* __restrict__ j_w,
                                             const float* __restrict__ k_w,
                                             unsigned* __restrict__ uo,
                                             int tbase) {
    int blk = blockIdx.x, tid = threadIdx.x;
    int tl = blk >> 9;  // 512 blocks per t (BB*HH/4/256 = 512)
    int t = tbase + tl;
    float mn2 = mn2f[t], s2 = s2f[t];
    size_t gi = (size_t)blk * 256 + tid;  // float4 index
    float4 v = ((const float4*)buf)[gi];
    int f0 = (tid & 63) * 4;  // float index within the 256-wide row
    bool isj = f0 < 128;
    const float* wp = isj ? j_w : k_w;
    int hh = isj ? f0 : f0 - 128;
    float4 wv = *(const float4*)&wp[hh];
    float4 r;
    r.x = sigf((v.x - mn2) * s2) * wv.x;
    r.y = sigf((v.y - mn2) * s2) * wv.y;
    r.z = sigf((v.z - mn2) * s2) * wv.z;
    r.w = sigf((v.w - mn2) * s2) * wv.w;
    ((float4*)buf)[gi] = r;
    float lmn = fminf(fminf(r.x, r.y), fminf(r.z, r.w));
    float lmx = fmaxf(fmaxf(r.x, r.y), fmaxf(r.z, r.w));
    float mnj = isj ? lmn : 3.4e38f, mxj = isj ? lmx : -3.4e38f;
    float mnk = isj ? 3.4e38f : lmn, mxk = isj ? -3.4e38f : lmx;
    __shared__ float r0[256], r1[256], r2[256], r3[256];
    r0[tid] = mnj; r1[tid] = mxj; r2[tid] = mnk; r3[tid] = mxk; __syncthreads();
    for (int s = 128; s > 0; s >>= 1) {
        if (tid < s) {
            r0[tid] = fminf(r0[tid], r0[tid + s]); r1[tid] = fmaxf(r1[tid], r1[tid + s]);
            r2[tid] = fminf(r2[tid], r2[tid + s]); r3[tid] = fmaxf(r3[tid], r3[tid + s]);
        }
        __syncthreads();
    }
    if (tid == 0) {
        atomicMin(&uo[1024 + t], f2o(r0[0])); atomicMax(&uo[1536 + t], f2o(r1[0]));
        atomicMin(&uo[2048 + t], f2o(r2[0])); atomicMax(&uo[2560 + t], f2o(r3[0]));
    }
}

// K3: affine scan over the chunk's t. One wave per batch row b, 2 h per lane, 8-deep prefetch.
__global__ __launch_bounds__(256) void k3_scan(const float* __restrict__ buf,
                                               const float* __restrict__ W4,
                                               const float* __restrict__ b4,
                                               const unsigned* __restrict__ uo,
                                               float2* __restrict__ statep,
                                               float* __restrict__ out4p,
                                               int tbase, int TC) {
    __shared__ float mj[512], sj[512], mk[512], sk[512];
    int tid = threadIdx.x;
    for (int tl = tid; tl < TC; tl += 256) {
        int t = tbase + tl;
        float mnj = o2f(uo[1024 + t]), mxj = o2f(uo[1536 + t]);
        float mnk = o2f(uo[2048 + t]), mxk = o2f(uo[2560 + t]);
        mj[tl] = mnj; sj[tl] = 20.0f / (mxj - mnj);
        mk[tl] = mnk; sk[tl] = 20.0f / (mxk - mnk);
    }
    __syncthreads();
    int wave = tid >> 6, lane = tid & 63;
    int b = blockIdx.x * 4 + wave;
    float w40 = W4[2 * lane], w41 = W4[2 * lane + 1];
    float bb4 = b4[0];
    float2 st = statep[b * 64 + lane];
    float s0 = st.x, s1 = st.y;
    const float2* basep = (const float2*)buf;  // float2 units
    const int rowstride = BB * 128;            // float2 per t-slice
    int off0 = b * 128 + lane;
    float2 jq[8], kq[8];
#pragma unroll
    for (int u = 0; u < 8; ++u) {
        if (u < TC) {
            jq[u] = basep[(size_t)u * rowstride + off0];
            kq[u] = basep[(size_t)u * rowstride + off0 + 64];
        }
    }
    for (int t0 = 0; t0 < TC; t0 += 8) {
#pragma unroll
        for (int u = 0; u < 8; ++u) {
            int tl = t0 + u;
            if (tl >= TC) break;
            float2 jp = jq[u], kp = kq[u];
            int tn = tl + 8;
            if (tn < TC) {
                jq[u] = basep[(size_t)tn * rowstride + off0];
                kq[u] = basep[(size_t)tn * rowstride + off0 + 64];
            }
            float ij0 = sigf((jp.x - mj[tl]) * sj[tl]);
            float ij1 = sigf((jp.y - mj[tl]) * sj[tl]);
            float ik0 = sigf((kp.x - mk[tl]) * sk[tl]);
            float ik1 = sigf((kp.y - mk[tl]) * sk[tl]);
            s0 = ij0 + s0 * (1.0f - ij0 - ik0);
            s1 = ij1 + s1 * (1.0f - ij1 - ik1);
            float r = s0 * w40 + s1 * w41;
#pragma unroll
            for (int m = 1; m < 64; m <<= 1) r += __shfl_xor(r, m);
            if (lane == 0) out4p[(size_t)b * TT + tbase + tl] = r + bb4;
        }
    }
    statep[b * 64 + lane] = make_float2(s0, s1);
}

__global__ __launch_bounds__(256) void k3b(const float* __restrict__ out4p,
                                           float* __restrict__ mn4f, float* __restrict__ s4f) {
    int t = blockIdx.x, tid = threadIdx.x;
    __shared__ float rmn[256], rmx[256];
    float mn = 3.4e38f, mx = -3.4e38f;
    for (int b = tid; b < BB; b += 256) {
        float v = out4p[(size_t)b * TT + t];
        mn = fminf(mn, v); mx = fmaxf(mx, v);
    }
    rmn[tid] = mn; rmx[tid] = mx; __syncthreads();
    for (int s = 128; s > 0; s >>= 1) {
        if (tid < s) { rmn[tid] = fminf(rmn[tid], rmn[tid + s]); rmx[tid] = fmaxf(rmx[tid], rmx[tid + s]); }
        __syncthreads();
    }
    if (tid == 0) { mn4f[t] = rmn[0]; s4f[t] = 20.0f / (rmx[0] - rmn[0]); }
}

__global__ __launch_bounds__(256) void k4_final(float* __restrict__ out,
                                                const float* __restrict__ mn4f,
                                                const float* __restrict__ s4f) {
    int i = blockIdx.x * 256 + threadIdx.x;  // float4 index, in-place on d_out
    float4 v = ((const float4*)out)[i];
    int t0 = (i * 4) & (TT - 1);
    float4 mn = *(const float4*)&mn4f[t0];
    float4 sc = *(const float4*)&s4f[t0];
    float4 r;
    r.x = sigf((v.x - mn.x) * sc.x);
    r.y = sigf((v.y - mn.y) * sc.y);
    r.z = sigf((v.z - mn.z) * sc.z);
    r.w = sigf((v.w - mn.w) * sc.w);
    ((float4*)out)[i] = r;
}

extern "C" void kernel_launch(void* const* d_in, const int* in_sizes, int n_in,
                              void* d_out, int out_size, void* d_ws, size_t ws_size,
                              hipStream_t stream) {
    const float* X  = (const float*)d_in[0];
    const float* W1 = (const float*)d_in[1];
    const float* b1 = (const float*)d_in[2];
    const float* W2 = (const float*)d_in[3];
    const float* b2 = (const float*)d_in[4];
    const float* W4 = (const float*)d_in[5];
    const float* b4 = (const float*)d_in[6];
    const float* j_w = (const float*)d_in[7];
    const float* k_w = (const float*)d_in[8];
    float* out = (float*)d_out;

    // Adaptive t-chunking: pick largest TC (power of 2) whose fp32 buffer fits ws.
    const size_t stateB = (size_t)BB * 128 * 4;  // 1 MB scan state
    const size_t statsB = 65536;                 // stats + atomic slots (24 KB used)
    int TC = 512;
    while (TC > 1 && ((size_t)TC * BB * HH * 4 + stateB + statsB) > ws_size) TC >>= 1;
    int NC = TT / TC;

    char* w = (char*)d_ws;
    float* buf = (float*)w;                                  // (TC,B,256) fp32
    size_t bufB = (size_t)TC * BB * HH * 4;
    float2* statep = (float2*)(w + bufB);                    // (B,64) float2 state
    float* fst = (float*)(w + bufB + stateB);
    float* mn1f = fst;        float* s1f = fst + 512;
    float* mn2f = fst + 1024; float* s2f = fst + 1536;
    float* mn4f = fst + 2048; float* s4f = fst + 2560;
    unsigned* uo = (unsigned*)(fst + 3072);                  // 6*512 ordered-uint atomic slots
    float* out4p = out;                                      // (B,T) pre-activation, in d_out

    k0_stats<<<512, 256, 0, stream>>>(X, W1, b1, mn1f, s1f, uo, statep);
    for (int c = 0; c < NC; ++c) {
        int tbase = c * TC;
        k1_gemm<<<dim3(32, 4, TC), 256, 0, stream>>>(X, W1, b1, W2, b2, mn1f, s1f, buf, uo, tbase);
        k1b<<<1, TC, 0, stream>>>(uo, mn2f, s2f, tbase);
        k2_jk<<<TC * 512, 256, 0, stream>>>(buf, mn2f, s2f, j_w, k_w, uo, tbase);
        k3_scan<<<512, 256, 0, stream>>>(buf, W4, b4, uo, statep, out4p, tbase, TC);
    }
    k3b<<<512, 256, 0, stream>>>(out4p, mn4f, s4f);
    k4_final<<<1024, 256, 0, stream>>>(out, mn4f, s4f);
}

// Round 3
// 916.603 us; speedup vs baseline: 5.7558x; 5.7558x over previous
//
#include <hip/hip_runtime.h>

#define TT 512
#define BB 2048
#define HH 256

typedef _Float16 f16x8 __attribute__((ext_vector_type(8)));
typedef _Float16 f16x4 __attribute__((ext_vector_type(4)));
typedef float f32x4 __attribute__((ext_vector_type(4)));

__device__ __forceinline__ float sigf(float z) { return 1.0f / (1.0f + __expf(-z)); }
// order-preserving float<->uint for atomic min/max
__device__ __forceinline__ unsigned f2o(float f) {
    unsigned u = __float_as_uint(f);
    return (u & 0x80000000u) ? ~u : (u | 0x80000000u);
}
__device__ __forceinline__ float o2f(unsigned o) {
    unsigned u = (o & 0x80000000u) ? (o & 0x7fffffffu) : ~o;
    return __uint_as_float(u);
}

// K0: per-t col min/max of X -> analytic out1 normalizer; init colG atomics + scan state.
__global__ __launch_bounds__(256) void k0_stats(const float* __restrict__ X,
                                                const float* __restrict__ W1,
                                                const float* __restrict__ b1,
                                                float* __restrict__ mn1f, float* __restrict__ s1f,
                                                unsigned* __restrict__ colGmn,
                                                unsigned* __restrict__ colGmx,
                                                float2* __restrict__ statep) {
    int t = blockIdx.x, tid = threadIdx.x;
    statep[blockIdx.x * 256 + tid] = make_float2(0.f, 0.f);  // ws never re-poisoned: re-init each launch
    colGmn[(size_t)t * 256 + tid] = 0xFFFFFFFFu;
    colGmx[(size_t)t * 256 + tid] = 0u;
    __shared__ float rmn[256], rmx[256];
    float mn = 3.4e38f, mx = -3.4e38f;
    for (int b = tid; b < BB; b += 256) {
        float v = X[(size_t)b * TT + t];
        mn = fminf(mn, v); mx = fmaxf(mx, v);
    }
    rmn[tid] = mn; rmx[tid] = mx; __syncthreads();
    for (int s = 128; s > 0; s >>= 1) {
        if (tid < s) { rmn[tid] = fminf(rmn[tid], rmn[tid + s]); rmx[tid] = fmaxf(rmx[tid], rmx[tid + s]); }
        __syncthreads();
    }
    float xmn = rmn[0], xmx = rmx[0];
    __syncthreads();
    float w = W1[tid], bb = b1[tid];
    float v0 = w * xmn + bb, v1 = w * xmx + bb;
    rmn[tid] = fminf(v0, v1); rmx[tid] = fmaxf(v0, v1); __syncthreads();
    for (int s = 128; s > 0; s >>= 1) {
        if (tid < s) { rmn[tid] = fminf(rmn[tid], rmn[tid + s]); rmx[tid] = fmaxf(rmx[tid], rmx[tid + s]); }
        __syncthreads();
    }
    if (tid == 0) {
        mn1f[t] = rmn[0];
        s1f[t] = 20.0f / (rmx[0] - rmn[0]);
    }
}

// K0b: W2 f32 -> f16 once per launch
__global__ __launch_bounds__(256) void k0b_cvt(const float* __restrict__ W2, _Float16* __restrict__ W2h) {
    int i4 = (blockIdx.x * 256 + threadIdx.x) * 4;
    float4 v = *(const float4*)&W2[i4];
    f16x4 h;
    h[0] = (_Float16)v.x; h[1] = (_Float16)v.y; h[2] = (_Float16)v.z; h[3] = (_Float16)v.w;
    *(f16x4*)&W2h[i4] = h;
}

// K1: f16-MFMA GEMM. out2_pre[tl,b,c] = sum_k out1[t,b,k]*W2[c,k] + b2[c], fp32 out.
// Block 512 thr (8 waves, 2x4), tile 128 rows x 256 cols (full N), K-chunks of 64.
// Epilogue collects per-(t,c) column min/max (LDS atomics -> global atomics).
__global__ __launch_bounds__(512) void k1_gemm(const float* __restrict__ X,
                                               const float* __restrict__ W1,
                                               const float* __restrict__ b1,
                                               const _Float16* __restrict__ W2h,
                                               const float* __restrict__ b2,
                                               const float* __restrict__ mn1f,
                                               const float* __restrict__ s1f,
                                               float* __restrict__ buf,
                                               unsigned* __restrict__ colGmn,
                                               unsigned* __restrict__ colGmx,
                                               int tbase) {
    int tl = blockIdx.z, t = tbase + tl;
    int bBase = blockIdx.x * 128;
    int tid = threadIdx.x;
    __shared__ __align__(16) _Float16 A_lds[128 * 72];
    __shared__ __align__(16) _Float16 B_lds[256 * 72];
    __shared__ float x_s[128];
    __shared__ unsigned cmnL[256], cmxL[256];
    if (tid < 128) x_s[tid] = X[(size_t)(bBase + tid) * TT + t];
    if (tid < 256) { cmnL[tid] = 0xFFFFFFFFu; cmxL[tid] = 0u; }
    float mn1 = mn1f[t], s1 = s1f[t];
    int lane = tid & 63, w = tid >> 6;
    int wr = w >> 2, wc = w & 3;             // wave tile: 64 rows x 64 cols
    int l15 = lane & 15, lk = (lane >> 4) * 8;
    f32x4 acc[4][4];
#pragma unroll
    for (int i = 0; i < 4; ++i)
#pragma unroll
        for (int j = 0; j < 4; ++j) acc[i][j] = (f32x4)0.0f;

    for (int kc = 0; kc < HH; kc += 64) {
        __syncthreads();
        // stage A = out1 (f16), [row][klocal], 2 vec8 per thread
#pragma unroll
        for (int it = 0; it < 2; ++it) {
            int idx = it * 512 + tid;
            int row = idx >> 3, kg = (idx & 7) * 8;
            float x = x_s[row];
            float4 wa = *(const float4*)&W1[kc + kg];
            float4 wb = *(const float4*)&W1[kc + kg + 4];
            float4 ba = *(const float4*)&b1[kc + kg];
            float4 bb = *(const float4*)&b1[kc + kg + 4];
            f16x8 av;
            av[0] = (_Float16)sigf((x * wa.x + ba.x - mn1) * s1);
            av[1] = (_Float16)sigf((x * wa.y + ba.y - mn1) * s1);
            av[2] = (_Float16)sigf((x * wa.z + ba.z - mn1) * s1);
            av[3] = (_Float16)sigf((x * wa.w + ba.w - mn1) * s1);
            av[4] = (_Float16)sigf((x * wb.x + bb.x - mn1) * s1);
            av[5] = (_Float16)sigf((x * wb.y + bb.y - mn1) * s1);
            av[6] = (_Float16)sigf((x * wb.z + bb.z - mn1) * s1);
            av[7] = (_Float16)sigf((x * wb.w + bb.w - mn1) * s1);
            *(f16x8*)&A_lds[row * 72 + kg] = av;
        }
        // stage B = W2h, [col][klocal], 4 vec8 per thread
#pragma unroll
        for (int it = 0; it < 4; ++it) {
            int idx = it * 512 + tid;
            int c = idx >> 3, kg = (idx & 7) * 8;
            *(f16x8*)&B_lds[c * 72 + kg] = *(const f16x8*)&W2h[(size_t)c * HH + kc + kg];
        }
        __syncthreads();
#pragma unroll
        for (int ks = 0; ks < 64; ks += 32) {
            f16x8 af[4], bf[4];
#pragma unroll
            for (int i = 0; i < 4; ++i)
                af[i] = *(const f16x8*)&A_lds[(wr * 64 + i * 16 + l15) * 72 + ks + lk];
#pragma unroll
            for (int j = 0; j < 4; ++j)
                bf[j] = *(const f16x8*)&B_lds[(wc * 64 + j * 16 + l15) * 72 + ks + lk];
#pragma unroll
            for (int i = 0; i < 4; ++i)
#pragma unroll
                for (int j = 0; j < 4; ++j)
                    acc[i][j] = __builtin_amdgcn_mfma_f32_16x16x32_f16(af[i], bf[j], acc[i][j], 0, 0, 0);
        }
    }
    // epilogue: +b2, store f32, per-col min/max
#pragma unroll
    for (int j = 0; j < 4; ++j) {
        int c = wc * 64 + j * 16 + l15;
        float b2v = b2[c];
        float vmn = 3.4e38f, vmx = -3.4e38f;
#pragma unroll
        for (int i = 0; i < 4; ++i) {
            int r0 = wr * 64 + i * 16 + ((lane >> 4) << 2);
#pragma unroll
            for (int q = 0; q < 4; ++q) {
                float v = acc[i][j][q] + b2v;
                buf[((size_t)tl * BB + bBase + r0 + q) * HH + c] = v;
                vmn = fminf(vmn, v); vmx = fmaxf(vmx, v);
            }
        }
        atomicMin(&cmnL[c], f2o(vmn));
        atomicMax(&cmxL[c], f2o(vmx));
    }
    __syncthreads();
    if (tid < 256) {
        atomicMin(&colGmn[(size_t)t * 256 + tid], cmnL[tid]);
        atomicMax(&colGmx[(size_t)t * 256 + tid], cmxL[tid]);
    }
}

// K1b: per-t analytic normalizers for out2 and (via sigmoid monotonicity) jpre/kpre.
__global__ __launch_bounds__(256) void k1b(const unsigned* __restrict__ colGmn,
                                           const unsigned* __restrict__ colGmx,
                                           const float* __restrict__ j_w,
                                           const float* __restrict__ k_w,
                                           float* __restrict__ mn2f, float* __restrict__ s2f,
                                           float* __restrict__ mjf, float* __restrict__ sjf,
                                           float* __restrict__ mkf, float* __restrict__ skf,
                                           int tbase) {
    int t = tbase + blockIdx.x, tid = threadIdx.x;
    __shared__ float ra[256], rb[256];
    float cmn = o2f(colGmn[(size_t)t * 256 + tid]);
    float cmx = o2f(colGmx[(size_t)t * 256 + tid]);
    ra[tid] = cmn; rb[tid] = cmx; __syncthreads();
    for (int s = 128; s > 0; s >>= 1) {
        if (tid < s) { ra[tid] = fminf(ra[tid], ra[tid + s]); rb[tid] = fmaxf(rb[tid], rb[tid + s]); }
        __syncthreads();
    }
    float mn2 = ra[0], mx2 = rb[0];
    float s2 = 20.0f / (mx2 - mn2);
    __syncthreads();
    // j: cols 0..127 (same fp expression the scan uses -> consistent extrema)
    float lo = 3.4e38f, hi = -3.4e38f;
    if (tid < 128) {
        float wv = j_w[tid];
        float a = sigf((cmn - mn2) * s2) * wv;
        float b = sigf((cmx - mn2) * s2) * wv;
        lo = fminf(a, b); hi = fmaxf(a, b);
    }
    ra[tid] = lo; rb[tid] = hi; __syncthreads();
    for (int s = 128; s > 0; s >>= 1) {
        if (tid < s) { ra[tid] = fminf(ra[tid], ra[tid + s]); rb[tid] = fmaxf(rb[tid], rb[tid + s]); }
        __syncthreads();
    }
    float mj = ra[0], mxj = rb[0];
    __syncthreads();
    // k: cols 128..255
    lo = 3.4e38f; hi = -3.4e38f;
    if (tid >= 128) {
        float wv = k_w[tid - 128];
        float a = sigf((cmn - mn2) * s2) * wv;
        float b = sigf((cmx - mn2) * s2) * wv;
        lo = fminf(a, b); hi = fmaxf(a, b);
    }
    ra[tid] = lo; rb[tid] = hi; __syncthreads();
    for (int s = 128; s > 0; s >>= 1) {
        if (tid < s) { ra[tid] = fminf(ra[tid], ra[tid + s]); rb[tid] = fmaxf(rb[tid], rb[tid + s]); }
        __syncthreads();
    }
    if (tid == 0) {
        mn2f[t] = mn2; s2f[t] = s2;
        mjf[t] = mj; sjf[t] = 20.0f / (ra[0] * 0.0f + rb[0] - mj);  // 20/(mxk... placeholder fixed below
    }
    // NOTE: above line writes sj using rb[0] which now holds mxk-tree result only after this
    // reduction; recompute cleanly:
    if (tid == 0) {
        float mk = ra[0], mxk = rb[0];
        mkf[t] = mk; skf[t] = 20.0f / (mxk - mk);
        sjf[t] = 20.0f / (mxj - mj);
    }
}

// K3: affine scan; computes jpre/kpre + gates on the fly from out2_pre.
__global__ __launch_bounds__(256) void k3_scan(const float* __restrict__ buf,
                                               const float* __restrict__ W4,
                                               const float* __restrict__ b4,
                                               const float* __restrict__ mn2f, const float* __restrict__ s2f,
                                               const float* __restrict__ mjf, const float* __restrict__ sjf,
                                               const float* __restrict__ mkf, const float* __restrict__ skf,
                                               const float* __restrict__ j_w, const float* __restrict__ k_w,
                                               float2* __restrict__ statep,
                                               float* __restrict__ out4p,
                                               int tbase, int TC) {
    __shared__ float n2L[512], c2L[512], mjL[512], sjL[512], mkL[512], skL[512];
    int tid = threadIdx.x;
    for (int tl = tid; tl < TC; tl += 256) {
        int t = tbase + tl;
        n2L[tl] = mn2f[t]; c2L[tl] = s2f[t];
        mjL[tl] = mjf[t]; sjL[tl] = sjf[t];
        mkL[tl] = mkf[t]; skL[tl] = skf[t];
    }
    __syncthreads();
    int wave = tid >> 6, lane = tid & 63;
    int b = blockIdx.x * 4 + wave;
    float w40 = W4[2 * lane], w41 = W4[2 * lane + 1];
    float jw0 = j_w[2 * lane], jw1 = j_w[2 * lane + 1];
    float kw0 = k_w[2 * lane], kw1 = k_w[2 * lane + 1];
    float bb4 = b4[0];
    float2 stv = statep[b * 64 + lane];
    float s0 = stv.x, s1v = stv.y;
    const float2* basep = (const float2*)buf;
    const int rowstride = BB * 128;
    int off0 = b * 128 + lane;
    float2 jq[8], kq[8];
#pragma unroll
    for (int u = 0; u < 8; ++u) {
        if (u < TC) {
            jq[u] = basep[(size_t)u * rowstride + off0];
            kq[u] = basep[(size_t)u * rowstride + off0 + 64];
        }
    }
    for (int t0 = 0; t0 < TC; t0 += 8) {
#pragma unroll
        for (int u = 0; u < 8; ++u) {
            int tl = t0 + u;
            if (tl >= TC) break;
            float2 jp = jq[u], kp = kq[u];
            int tn = tl + 8;
            if (tn < TC) {
                jq[u] = basep[(size_t)tn * rowstride + off0];
                kq[u] = basep[(size_t)tn * rowstride + off0 + 64];
            }
            float n2 = n2L[tl], c2 = c2L[tl];
            float pj0 = sigf((jp.x - n2) * c2) * jw0;
            float pj1 = sigf((jp.y - n2) * c2) * jw1;
            float pk0 = sigf((kp.x - n2) * c2) * kw0;
            float pk1 = sigf((kp.y - n2) * c2) * kw1;
            float ij0 = sigf((pj0 - mjL[tl]) * sjL[tl]);
            float ij1 = sigf((pj1 - mjL[tl]) * sjL[tl]);
            float ik0 = sigf((pk0 - mkL[tl]) * skL[tl]);
            float ik1 = sigf((pk1 - mkL[tl]) * skL[tl]);
            s0 = ij0 + s0 * (1.0f - ij0 - ik0);
            s1v = ij1 + s1v * (1.0f - ij1 - ik1);
            float r = s0 * w40 + s1v * w41;
#pragma unroll
            for (int m = 1; m < 64; m <<= 1) r += __shfl_xor(r, m);
            if (lane == 0) out4p[(size_t)b * TT + tbase + tl] = r + bb4;
        }
    }
    statep[b * 64 + lane] = make_float2(s0, s1v);
}

__global__ __launch_bounds__(256) void k3b(const float* __restrict__ out4p,
                                           float* __restrict__ mn4f, float* __restrict__ s4f) {
    int t = blockIdx.x, tid = threadIdx.x;
    __shared__ float rmn[256], rmx[256];
    float mn = 3.4e38f, mx = -3.4e38f;
    for (int b = tid; b < BB; b += 256) {
        float v = out4p[(size_t)b * TT + t];
        mn = fminf(mn, v); mx = fmaxf(mx, v);
    }
    rmn[tid] = mn; rmx[tid] = mx; __syncthreads();
    for (int s = 128; s > 0; s >>= 1) {
        if (tid < s) { rmn[tid] = fminf(rmn[tid], rmn[tid + s]); rmx[tid] = fmaxf(rmx[tid], rmx[tid + s]); }
        __syncthreads();
    }
    if (tid == 0) { mn4f[t] = rmn[0]; s4f[t] = 20.0f / (rmx[0] - rmn[0]); }
}

__global__ __launch_bounds__(256) void k4_final(float* __restrict__ out,
                                                const float* __restrict__ mn4f,
                                                const float* __restrict__ s4f) {
    int i = blockIdx.x * 256 + threadIdx.x;
    float4 v = ((const float4*)out)[i];
    int t0 = (i * 4) & (TT - 1);
    float4 mn = *(const float4*)&mn4f[t0];
    float4 sc = *(const float4*)&s4f[t0];
    float4 r;
    r.x = sigf((v.x - mn.x) * sc.x);
    r.y = sigf((v.y - mn.y) * sc.y);
    r.z = sigf((v.z - mn.z) * sc.z);
    r.w = sigf((v.w - mn.w) * sc.w);
    ((float4*)out)[i] = r;
}

extern "C" void kernel_launch(void* const* d_in, const int* in_sizes, int n_in,
                              void* d_out, int out_size, void* d_ws, size_t ws_size,
                              hipStream_t stream) {
    const float* X  = (const float*)d_in[0];
    const float* W1 = (const float*)d_in[1];
    const float* b1 = (const float*)d_in[2];
    const float* W2 = (const float*)d_in[3];
    const float* b2 = (const float*)d_in[4];
    const float* W4 = (const float*)d_in[5];
    const float* b4 = (const float*)d_in[6];
    const float* j_w = (const float*)d_in[7];
    const float* k_w = (const float*)d_in[8];
    float* out = (float*)d_out;

    const size_t stateB = (size_t)BB * 64 * sizeof(float2);  // 1 MB
    const size_t colGB  = (size_t)TT * 256 * 2 * 4;          // 1 MB
    const size_t w2hB   = (size_t)HH * HH * 2;               // 128 KB
    const size_t statsB = 65536;
    int TC = 512;
    while (TC > 8 && ((size_t)TC * BB * HH * 4 + stateB + colGB + w2hB + statsB) > ws_size) TC >>= 1;
    int NC = TT / TC;

    char* w = (char*)d_ws;
    float* buf = (float*)w;
    size_t off = (size_t)TC * BB * HH * 4;
    float2* statep = (float2*)(w + off); off += stateB;
    unsigned* colGmn = (unsigned*)(w + off); off += colGB / 2;
    unsigned* colGmx = (unsigned*)(w + off); off += colGB / 2;
    _Float16* W2h = (_Float16*)(w + off); off += w2hB;
    float* fst = (float*)(w + off);
    float* mn1f = fst;        float* s1f = fst + 512;
    float* mn2f = fst + 1024; float* s2f = fst + 1536;
    float* mjf  = fst + 2048; float* sjf = fst + 2560;
    float* mkf  = fst + 3072; float* skf = fst + 3584;
    float* mn4f = fst + 4096; float* s4f = fst + 4608;
    float* out4p = out;  // (B,T) pre-activation lives in d_out, normalized in place

    k0_stats<<<512, 256, 0, stream>>>(X, W1, b1, mn1f, s1f, colGmn, colGmx, statep);
    k0b_cvt<<<64, 256, 0, stream>>>(W2, W2h);
    for (int c = 0; c < NC; ++c) {
        int tbase = c * TC;
        k1_gemm<<<dim3(BB / 128, 1, TC), 512, 0, stream>>>(X, W1, b1, W2h, b2, mn1f, s1f,
                                                           buf, colGmn, colGmx, tbase);
        k1b<<<TC, 256, 0, stream>>>(colGmn, colGmx, j_w, k_w, mn2f, s2f, mjf, sjf, mkf, skf, tbase);
        k3_scan<<<512, 256, 0, stream>>>(buf, W4, b4, mn2f, s2f, mjf, sjf, mkf, skf,
                                         j_w, k_w, statep, out4p, tbase, TC);
    }
    k3b<<<512, 256, 0, stream>>>(out4p, mn4f, s4f);
    k4_final<<<1024, 256, 0, stream>>>(out, mn4f, s4f);
}